// Round 14
// baseline (186.128 us; speedup 1.0000x reference)
//
#include <hip/hip_runtime.h>

// Problem constants (fixed by setup_inputs): B=64, T=1024, V=128, S=256
constexpr int B_ = 64;
constexpr int T_ = 1024;
constexpr int V_ = 128;
constexpr int S_ = 256;
constexpr float INV_LN2 = 1.4426950408889634f;
constexpr float LN2 = 0.6931471805599453f;
constexpr unsigned MAGIC = 0x5AD0F00Du;   // != 0xAA poison pattern, != 0

#define WG_SCOPE __HIP_MEMORY_SCOPE_WORKGROUP
#define AG_SCOPE __HIP_MEMORY_SCOPE_AGENT

// DPP cross-lane move (VALU pipe). old=0, bound_ctrl=false: OOB source -> 0.
template<int CTRL>
__device__ __forceinline__ float dppf(float x) {
    return __int_as_float(__builtin_amdgcn_update_dpp(
        0, __float_as_int(x), CTRL, 0xF, 0xF, false));
}
constexpr int DPP_WAVE_SHR1 = 0x138;   // lane i <- lane i-1 (lane 0 -> 0)
constexpr int DPP_WAVE_SHL1 = 0x130;   // lane i <- lane i+1 (lane 63 -> 0)
constexpr int DPP_ROW_SHR1  = 0x111;
constexpr int DPP_ROW_SHR2  = 0x112;
constexpr int DPP_ROW_SHR4  = 0x114;
constexpr int DPP_ROW_SHR8  = 0x118;
constexpr int DPP_BCAST15   = 0x142;
constexpr int DPP_BCAST31   = 0x143;

// Wave-uniform rescale via DPP max-reduce: pin wave max into [2^123, 2^124).
// R8/R10-proven numerics: 8-row period (16-row variant underflows — R9).
__device__ __forceinline__ int wave_rescale(float a[10], int& K) {
    float mx = a[0];
    #pragma unroll
    for (int k = 1; k < 10; ++k) mx = fmaxf(mx, a[k]);
    mx = fmaxf(mx, dppf<DPP_ROW_SHR1>(mx));
    mx = fmaxf(mx, dppf<DPP_ROW_SHR2>(mx));
    mx = fmaxf(mx, dppf<DPP_ROW_SHR4>(mx));
    mx = fmaxf(mx, dppf<DPP_ROW_SHR8>(mx));
    mx = fmaxf(mx, dppf<DPP_BCAST15>(mx));
    mx = fmaxf(mx, dppf<DPP_BCAST31>(mx));   // lane 63 = wave max
    const unsigned mb = (unsigned)__builtin_amdgcn_readlane(__float_as_uint(mx), 63);
    const int ks = (mb != 0u) ? (250 - (int)(mb >> 23)) : 0;
    #pragma unroll
    for (int k = 0; k < 10; ++k) a[k] = ldexpf(a[k], ks);
    K += ks;
    return ks;
}

// No-handoff design: each consumer wave gathers its own 6 probs/row straight
// from global (lp is L2/L3-resident) with a static two-set register pipeline
// (no producers, no tags, no polls, no LDS ring). 1 block / batch element,
// 128 threads: wid0 = forward alpha (+ join + reduce), wid1 = backward beta.
__global__ __launch_bounds__(128) void ctc_direct(
    const float* __restrict__ lp,      // [B,T,V] natural-log softmax
    const int* __restrict__ in_len,    // [B]
    const int* __restrict__ tgt,       // [B,S]
    const int* __restrict__ tgt_len,   // [B]
    float* __restrict__ wloss,         // [B]  global scratch
    int* __restrict__ wflag,           // [B]  global scratch (poisoned != MAGIC)
    float* __restrict__ out)           // [1]
{
    const int b    = blockIdx.x;
    const int tid  = threadIdx.x;
    const int wid  = tid >> 6;
    const int lane = tid & 63;

    __shared__ float dumpB[640];
    __shared__ int   consB;
    __shared__ int   KBsh;

    const int L  = tgt_len[b];        // 64..256
    const int Tb = in_len[b];         // 768..1024
    const float* lpb = lp + (size_t)b * T_ * V_;
    const int* tg = tgt + b * S_;

    const int tm = (Tb - 2) >> 1;
    const int Uf = tm;                // fwd steps: u=1..Uf (row t=u) -> alpha_tm
    const int Ub = Tb - 2 - tm;       // bwd steps: u=1..Ub (row t=Tb-1-u) -> g_{tm+1}

    if (tid == 0) consB = 0;
    __syncthreads();

    if (wid == 1) {
        // ======================= backward consumer =======================
        const int U = Ub;
        int   labE[5];
        float vmask[5];
        float sB[5];
        #pragma unroll
        for (int c = 0; c < 5; ++c) {
            const int j = 5 * lane + c;
            labE[c]  = (j < L) ? tg[j] : 0;
            vmask[c] = (j < L) ? 1.0f : 0.0f;
            const int j2 = j + 1;
            sB[c] = (j2 < L && tg[j2] != tg[j2 - 1]) ? 1.0f : 0.0f;
        }
        float g[10];
        #pragma unroll
        for (int k = 0; k < 10; ++k) g[k] = 0.0f;
        {   // g_{Tb-1}: nonzero at s=2L (blank) and s=2L-1 (last label)
            const float pb = __builtin_exp2f(lpb[(size_t)(Tb - 1) * V_] * INV_LN2);
            const float pl = __builtin_exp2f(lpb[(size_t)(Tb - 1) * V_ + tg[L - 1]] * INV_LN2);
            #pragma unroll
            for (int k = 0; k < 10; ++k) {
                const int s = 10 * lane + k;
                if (s == 2 * L)     g[k] = pb;
                if (s == 2 * L - 1) g[k] = pl;
            }
        }
        float d0n = dppf<DPP_WAVE_SHL1>(g[0]);
        float d1n = dppf<DPP_WAVE_SHL1>(g[1]);
        int K = 0;

        float G0[24], G1[24];          // two 4-row blocks of raw logits
        auto issue = [&](float (&G)[24], int m) {
            #pragma unroll
            for (int r = 0; r < 4; ++r) {
                int u = 4 * m + 1 + r; u = (u <= U) ? u : U;   // clamp: dead-but-safe
                const float* row = lpb + (size_t)(Tb - 1 - u) * V_;
                G[6 * r] = row[0];
                #pragma unroll
                for (int c = 0; c < 5; ++c) G[6 * r + 1 + c] = row[labE[c]];
            }
        };
        auto rowCore = [&](float p0, float q1, float q3, float q5, float q7, float q9) {
            const float d0 = d0n, d1 = d1n;
            g[0] = (g[0] + g[1]) * p0;
            g[1] = (g[1] + g[2] + sB[0] * g[3]) * q1;
            d0n = dppf<DPP_WAVE_SHL1>(g[0]);
            d1n = dppf<DPP_WAVE_SHL1>(g[1]);
            g[2] = (g[2] + g[3]) * p0;
            g[3] = (g[3] + g[4] + sB[1] * g[5]) * q3;
            g[4] = (g[4] + g[5]) * p0;
            g[5] = (g[5] + g[6] + sB[2] * g[7]) * q5;
            g[6] = (g[6] + g[7]) * p0;
            g[7] = (g[7] + g[8] + sB[3] * g[9]) * q7;
            g[8] = (g[8] + g[9]) * p0;
            g[9] = (g[9] + d0 + sB[4] * d1) * q9;
        };
        auto proc4 = [&](const float (&G)[24]) {
            #pragma unroll
            for (int r = 0; r < 4; ++r) {
                float e[6];
                e[0] = __builtin_exp2f(G[6 * r] * INV_LN2);
                #pragma unroll
                for (int c = 0; c < 5; ++c)
                    e[c + 1] = vmask[c] * __builtin_exp2f(G[6 * r + 1 + c] * INV_LN2);
                rowCore(e[0], e[1], e[2], e[3], e[4], e[5]);
            }
        };

        const int FB = U >> 2;         // full 4-row blocks (>= 95)
        issue(G0, 0); issue(G1, 1);
        int mb = 0;
        for (; mb + 2 <= FB; mb += 2) {
            proc4(G0); issue(G0, mb + 2);       // refill after consumption
            proc4(G1); issue(G1, mb + 3);
            { const int ks = wave_rescale(g, K);
              d0n = ldexpf(d0n, ks); d1n = ldexpf(d1n, ks); }   // 8-row period
        }
        if (mb < FB) {                 // FB odd: last full block sits in G0
            proc4(G0);
            { const int ks = wave_rescale(g, K);
              d0n = ldexpf(d0n, ks); d1n = ldexpf(d1n, ks); }
        }
        for (int u = 4 * FB + 1; u <= U; ++u) {   // remainder rows (<=3)
            const float* row = lpb + (size_t)(Tb - 1 - u) * V_;
            float e[6];
            e[0] = __builtin_exp2f(row[0] * INV_LN2);
            #pragma unroll
            for (int c = 0; c < 5; ++c)
                e[c + 1] = vmask[c] * __builtin_exp2f(row[labE[c]] * INV_LN2);
            rowCore(e[0], e[1], e[2], e[3], e[4], e[5]);
        }

        {   // combine: gext[s] = g[s] + g[s+1] + skip[s+2]*g[s+2] (ascending)
            const float d0 = d0n, d1 = d1n;
            g[0] = g[0] + g[1];
            g[1] = g[1] + g[2] + sB[0] * g[3];
            g[2] = g[2] + g[3];
            g[3] = g[3] + g[4] + sB[1] * g[5];
            g[4] = g[4] + g[5];
            g[5] = g[5] + g[6] + sB[2] * g[7];
            g[6] = g[6] + g[7];
            g[7] = g[7] + g[8] + sB[3] * g[9];
            g[8] = g[8] + g[9];
            g[9] = g[9] + d0 + sB[4] * d1;
        }
        #pragma unroll
        for (int k = 0; k < 10; ++k) dumpB[10 * lane + k] = g[k];
        if (lane == 0) {
            KBsh = K;
            // ds ops retire in order per wave -> this store publishes dumpB/KBsh
            __hip_atomic_store(&consB, 1, __ATOMIC_RELAXED, WG_SCOPE);
        }
        return;
    }

    // ======================= forward consumer (wid 0) =======================
    const int U = Uf;
    int   labE[5];
    float vmask[5];
    float skipf[5];
    #pragma unroll
    for (int c = 0; c < 5; ++c) {
        const int j = 5 * lane + c;
        labE[c]  = (j < L) ? tg[j] : 0;
        vmask[c] = (j < L) ? 1.0f : 0.0f;
        skipf[c] = (j >= 1 && j < L && tg[j] != tg[j - 1]) ? 1.0f : 0.0f;
    }
    float a[10];
    #pragma unroll
    for (int k = 0; k < 10; ++k) a[k] = 0.0f;
    {
        const float p00 = __builtin_exp2f(lpb[0] * INV_LN2);
        const float p01 = __builtin_exp2f(lpb[tg[0]] * INV_LN2);
        if (lane == 0) { a[0] = p00; a[1] = p01; }
    }
    float u9n = 0.0f;
    int K = 0;

    float G0[24], G1[24];
    auto issue = [&](float (&G)[24], int m) {
        #pragma unroll
        for (int r = 0; r < 4; ++r) {
            int u = 4 * m + 1 + r; u = (u <= U) ? u : U;
            const float* row = lpb + (size_t)u * V_;
            G[6 * r] = row[0];
            #pragma unroll
            for (int c = 0; c < 5; ++c) G[6 * r + 1 + c] = row[labE[c]];
        }
    };
    auto rowCore = [&](float p0, float q1, float q3, float q5, float q7, float q9) {
        const float u9 = u9n;
        a[9] = (a[9] + a[8] + skipf[4] * a[7]) * q9;
        u9n = dppf<DPP_WAVE_SHR1>(a[9]);
        a[8] = (a[8] + a[7]) * p0;
        a[7] = (a[7] + a[6] + skipf[3] * a[5]) * q7;
        a[6] = (a[6] + a[5]) * p0;
        a[5] = (a[5] + a[4] + skipf[2] * a[3]) * q5;
        a[4] = (a[4] + a[3]) * p0;
        a[3] = (a[3] + a[2] + skipf[1] * a[1]) * q3;
        a[2] = (a[2] + a[1]) * p0;
        a[1] = (a[1] + a[0] + skipf[0] * u9) * q1;
        a[0] = (a[0] + u9) * p0;
    };
    auto proc4 = [&](const float (&G)[24]) {
        #pragma unroll
        for (int r = 0; r < 4; ++r) {
            float e[6];
            e[0] = __builtin_exp2f(G[6 * r] * INV_LN2);
            #pragma unroll
            for (int c = 0; c < 5; ++c)
                e[c + 1] = vmask[c] * __builtin_exp2f(G[6 * r + 1 + c] * INV_LN2);
            rowCore(e[0], e[1], e[2], e[3], e[4], e[5]);
        }
    };

    const int FB = U >> 2;
    issue(G0, 0); issue(G1, 1);
    int mb = 0;
    for (; mb + 2 <= FB; mb += 2) {
        proc4(G0); issue(G0, mb + 2);
        proc4(G1); issue(G1, mb + 3);
        { const int ks = wave_rescale(a, K); u9n = ldexpf(u9n, ks); }
    }
    if (mb < FB) {
        proc4(G0);
        { const int ks = wave_rescale(a, K); u9n = ldexpf(u9n, ks); }
    }
    for (int u = 4 * FB + 1; u <= U; ++u) {
        const float* row = lpb + (size_t)u * V_;
        float e[6];
        e[0] = __builtin_exp2f(row[0] * INV_LN2);
        #pragma unroll
        for (int c = 0; c < 5; ++c)
            e[c + 1] = vmask[c] * __builtin_exp2f(row[labE[c]] * INV_LN2);
        rowCore(e[0], e[1], e[2], e[3], e[4], e[5]);
    }

    // ---- join: wait for bwd wave, dot in DOUBLE (R7 lesson: f32 denormal-flush) ----
    while (__hip_atomic_load(&consB, __ATOMIC_RELAXED, WG_SCOPE) != 1)
        __builtin_amdgcn_s_sleep(1);
    double sum = 0.0;
    #pragma unroll
    for (int k = 0; k < 10; ++k)
        sum += (double)a[k] * (double)dumpB[10 * lane + k];
    #pragma unroll
    for (int d = 1; d < 64; d <<= 1) sum += __shfl_xor(sum, d, 64);

    if (lane == 0) {
        float loss = 0.0f;                     // infeasible (sum<=0) -> 0
        if (sum > 0.0) {
            const long long ub2 = __double_as_longlong(sum);
            const int ex = (int)((ub2 >> 52) & 2047) - 1023;
            const double f = __longlong_as_double(
                (ub2 & 0x000FFFFFFFFFFFFFLL) | 0x3FF0000000000000LL);
            const float ll2 = __builtin_log2f((float)f) + (float)(ex - K - KBsh);
            loss = -(ll2 * LN2);
            if (!(loss <= 1e29f)) loss = 0.0f; // zero_infinity
        }
        wloss[b] = loss / (float)L;
        __hip_atomic_store(&wflag[b], (int)MAGIC, __ATOMIC_RELEASE, AG_SCOPE);
    }

    // ---- block 0: final mean over 64 batch losses (single-dispatch reduce).
    // 64 blocks on 256 CUs are co-resident, so the spin cannot deadlock.
    if (b == 0) {
        while ((unsigned)__hip_atomic_load(&wflag[lane], __ATOMIC_ACQUIRE, AG_SCOPE) != MAGIC)
            __builtin_amdgcn_s_sleep(1);
        float v = wloss[lane];                 // ordered after own flag's acquire
        #pragma unroll
        for (int o = 1; o < 64; o <<= 1) v += __shfl_xor(v, o, 64);
        if (lane == 0) out[0] = v / (float)B_;
    }
}

extern "C" void kernel_launch(void* const* d_in, const int* in_sizes, int n_in,
                              void* d_out, int out_size, void* d_ws, size_t ws_size,
                              hipStream_t stream) {
    const float* lp      = (const float*)d_in[0];
    const int*   in_len  = (const int*)d_in[1];
    const int*   tgt     = (const int*)d_in[2];
    const int*   tgt_len = (const int*)d_in[3];
    float* wloss = (float*)d_ws;                       // 64 floats
    int*   wflag = (int*)((char*)d_ws + 256);          // 64 ints
    float* out   = (float*)d_out;

    ctc_direct<<<B_, 128, 0, stream>>>(lp, in_len, tgt, tgt_len, wloss, wflag, out);
}